// Round 1
// baseline (90.125 us; speedup 1.0000x reference)
//
#include <hip/hip_runtime.h>
#include <math.h>

#define NQ 5
#define DIM 32

// ---------------- Kernel 1: build folded quadratic-form matrices A[2][32][32] ----------------
// One block, 1024 threads = 32 columns x 32 amplitude rows.
// Each thread holds ONE complex amplitude (ax,ay) of basis-column `col` in registers;
// gate pair-exchanges go through __shfl_xor (mask < 32 stays inside the 32-lane column group).
// Bit convention: qubit q <-> bit (4-q) of the flat state index (q0 = MSB), mask m = 16>>q.

__device__ inline void rx_step(float& ax, float& ay, int m, float c, float sn) {
    // RX matrix is symmetric: new = c*v + (-i*sn)*partner for BOTH bit values (branchless)
    float px = __shfl_xor(ax, m);
    float py = __shfl_xor(ay, m);
    float nx = c * ax + sn * py;
    float ny = c * ay - sn * px;
    ax = nx; ay = ny;
}

__device__ inline void ry_step(float& ax, float& ay, int k, int m, float c, float sn) {
    float px = __shfl_xor(ax, m);
    float py = __shfl_xor(ay, m);
    float f = (k & m) ? sn : -sn;   // bit0: c*v - sn*p ; bit1: c*v + sn*p
    ax = c * ax + f * px;
    ay = c * ay + f * py;
}

__device__ inline void cnot_step(float& ax, float& ay, int k, int mc, int mt) {
    float px = __shfl_xor(ax, mt);
    float py = __shfl_xor(ay, mt);
    if (k & mc) { ax = px; ay = py; }
}

__global__ __launch_bounds__(1024) void build_A_kernel(
        const float* __restrict__ conv, const float* __restrict__ pool,
        const float* __restrict__ fcw, float* __restrict__ A) {
    const int tid  = threadIdx.x;
    const int col  = tid >> 5;      // basis column this thread helps simulate
    const int k    = tid & 31;      // amplitude (row) index held by this thread

    float ax = (k == col) ? 1.0f : 0.0f;   // state = e_col
    float ay = 0.0f;

    int wires[NQ] = {0, 1, 2, 3, 4};
    int nw = NQ;
    const float S2 = 0.70710678118654752440f;  // cos(pi/4) = sin(pi/4)

    #pragma unroll
    for (int l = 0; l < 2; ++l) {
        const float* w = conv + l * 15;
        for (int i = 0; i < nw; ++i) {
            const int a = wires[i], b = wires[(i + 1) % nw];
            const int ma = 16 >> a, mb = 16 >> b;
            // CNOT;RZ(b,w[i]);CNOT  ==  RZZ(a,b,w[i])  (diagonal, phase by parity)
            {
                float c, sn; __sincosf(0.5f * w[i], &sn, &c);
                float eim = ((((k & ma) != 0) ^ (((k & mb) != 0)))) ? sn : -sn;
                float nx = c * ax - eim * ay;
                float ny = c * ay + eim * ax;
                ax = nx; ay = ny;
            }
            rx_step(ax, ay, ma, S2, S2);    // RX(a,+pi/2)
            rx_step(ax, ay, mb, S2, S2);    // RX(b,+pi/2)
            cnot_step(ax, ay, k, ma, mb);   // CNOT(a,b)
            rx_step(ax, ay, ma, S2, -S2);   // RX(a,-pi/2)
            rx_step(ax, ay, mb, S2, -S2);   // RX(b,-pi/2)
            // CZ;RZ(b,w[i+2]);CZ == RZ(b,w[i+2])  (all diagonal, CZ^2 = I)
            {
                float c, sn; __sincosf(0.5f * w[i + 2], &sn, &c);
                float eim = (k & mb) ? sn : -sn;
                float nx = c * ax - eim * ay;
                float ny = c * ay + eim * ax;
                ax = nx; ay = ny;
            }
        }
        // pool block
        {
            const float* pw = pool + l * 2;
            const int a = wires[0], b = wires[1];
            const int ma = 16 >> a, mb = 16 >> b;
            float c0, s0v, c1, s1v;
            __sincosf(0.5f * pw[0], &s0v, &c0);
            __sincosf(0.5f * pw[1], &s1v, &c1);
            ry_step(ax, ay, k, ma, c0, s0v);     // RY(a, pw0)
            ry_step(ax, ay, k, mb, c1, s1v);     // RY(b, pw1)
            cnot_step(ax, ay, k, ma, mb);        // CNOT(a,b)
            // CRY(ctrl=b, tgt=a, pw0)
            {
                float px = __shfl_xor(ax, ma);
                float py = __shfl_xor(ay, ma);
                if (k & mb) {
                    float f = (k & ma) ? s0v : -s0v;
                    float nx = c0 * ax + f * px;
                    float ny = c0 * ay + f * py;
                    ax = nx; ay = ny;
                }
            }
            // CRX(ctrl=a, tgt=b, pw1)
            {
                float px = __shfl_xor(ax, mb);
                float py = __shfl_xor(ay, mb);
                if (k & ma) {
                    float nx = c1 * ax + s1v * py;
                    float ny = c1 * ay - s1v * px;
                    ax = nx; ay = ny;
                }
            }
            cnot_step(ax, ay, k, mb, ma);        // CNOT(b,a)
        }
        for (int q = 0; q < nw - 1; ++q) wires[q] = wires[q + 1];
        nw--;
    }

    // thread holds U[k][col]; share all columns
    __shared__ float2 U[DIM][DIM + 1];
    U[col][k] = make_float2(ax, ay);
    __syncthreads();

    // measured wires after 2 layers: [2,3] -> bit masks 4 and 2
    // A_c[s][t] = sum_k (fcw[c,0]*z2(k) + fcw[c,1]*z3(k)) * Re(conj(U[k,s]) U[k,t])
    const int s = tid >> 5, t = tid & 31;
    const float w00 = fcw[0], w01 = fcw[1], w10 = fcw[2], w11 = fcw[3];
    float acc0 = 0.0f, acc1 = 0.0f;
    #pragma unroll
    for (int kk = 0; kk < DIM; ++kk) {
        float2 us = U[s][kk];
        float2 ut = U[t][kk];
        float d = us.x * ut.x + us.y * ut.y;
        float d2 = (kk & 4) ? -d : d;
        float d3 = (kk & 2) ? -d : d;
        acc0 += w00 * d2 + w01 * d3;
        acc1 += w10 * d2 + w11 * d3;
    }
    // fold symmetry: keep upper triangle, double off-diagonals, zero lower
    float f0 = (t < s) ? 0.0f : ((t == s) ? acc0 : 2.0f * acc0);
    float f1 = (t < s) ? 0.0f : ((t == s) ? acc1 : 2.0f * acc1);
    A[s * DIM + t]            = f0;
    A[DIM * DIM + s * DIM + t] = f1;
}

// ---------------- Kernel 2: per-batch-element evaluation ----------------
__global__ __launch_bounds__(256) void qcnn_eval_kernel(
        const float* __restrict__ x, const float* __restrict__ A,
        const float* __restrict__ fcb, float* __restrict__ out, int nB) {
    __shared__ float Ash[2 * DIM * DIM];
    for (int i = threadIdx.x; i < 2 * DIM * DIM; i += 256) Ash[i] = A[i];
    __syncthreads();

    const int b = blockIdx.x * 256 + threadIdx.x;
    if (b >= nB) return;

    float cs[NQ], sn[NQ];
    #pragma unroll
    for (int q = 0; q < NQ; ++q) {
        float xv = x[b * NQ + q];
        __sincosf(0.5f * xv, &sn[q], &cs[q]);
    }
    // s0[s] = prod_q a_q[bit_q(s)], qubit0 = MSB
    float v01[4];
    v01[0] = cs[0] * cs[1]; v01[1] = cs[0] * sn[1];
    v01[2] = sn[0] * cs[1]; v01[3] = sn[0] * sn[1];
    float v23[4];
    v23[0] = cs[2] * cs[3]; v23[1] = cs[2] * sn[3];
    v23[2] = sn[2] * cs[3]; v23[3] = sn[2] * sn[3];
    float v234[8];
    #pragma unroll
    for (int i = 0; i < 4; ++i) {
        v234[2 * i]     = v23[i] * cs[4];
        v234[2 * i + 1] = v23[i] * sn[4];
    }
    float s0[DIM];
    #pragma unroll
    for (int s = 0; s < DIM; ++s) s0[s] = v01[s >> 3] * v234[s & 7];

    // out[c] = s0^T Afold_c s0 + fcb[c]  (upper-triangular fold, off-diag pre-doubled)
    float res0 = fcb[0], res1 = fcb[1];
    #pragma unroll
    for (int si = 0; si < DIM; ++si) {
        float row0 = 0.0f, row1 = 0.0f;
        #pragma unroll
        for (int t = si; t < DIM; ++t) {
            row0 += Ash[si * DIM + t] * s0[t];
            row1 += Ash[DIM * DIM + si * DIM + t] * s0[t];
        }
        res0 += s0[si] * row0;
        res1 += s0[si] * row1;
    }
    reinterpret_cast<float2*>(out)[b] = make_float2(res0, res1);
}

// ---------------- launch ----------------
extern "C" void kernel_launch(void* const* d_in, const int* in_sizes, int n_in,
                              void* d_out, int out_size, void* d_ws, size_t ws_size,
                              hipStream_t stream) {
    const float* x    = (const float*)d_in[0];
    const float* conv = (const float*)d_in[1];
    const float* pool = (const float*)d_in[2];
    const float* fcw  = (const float*)d_in[3];
    const float* fcb  = (const float*)d_in[4];
    float* out = (float*)d_out;
    float* A   = (float*)d_ws;   // 2*32*32 floats = 8 KB

    const int nB = in_sizes[0] / NQ;

    hipLaunchKernelGGL(build_A_kernel, dim3(1), dim3(1024), 0, stream,
                       conv, pool, fcw, A);
    hipLaunchKernelGGL(qcnn_eval_kernel, dim3((nB + 255) / 256), dim3(256), 0, stream,
                       x, A, fcb, out, nB);
}

// Round 2
// 83.794 us; speedup vs baseline: 1.0755x; 1.0755x over previous
//
#include <hip/hip_runtime.h>
#include <math.h>

#define NQ 5
#define DIM 32

// ---------------- Kernel 1: build folded quadratic-form matrices A[2][32][32] ----------------
// One block, 1024 threads = 32 columns x 32 amplitude rows.
// Each thread holds ONE complex amplitude (ax,ay) of basis-column `col` in registers;
// gate pair-exchanges go through __shfl_xor (mask < 32 stays inside the 32-lane column group).
// Bit convention: qubit q <-> bit (4-q) of the flat state index (q0 = MSB), mask m = 16>>q.

__device__ inline void rx_step(float& ax, float& ay, int m, float c, float sn) {
    float px = __shfl_xor(ax, m);
    float py = __shfl_xor(ay, m);
    float nx = c * ax + sn * py;
    float ny = c * ay - sn * px;
    ax = nx; ay = ny;
}

__device__ inline void ry_step(float& ax, float& ay, int k, int m, float c, float sn) {
    float px = __shfl_xor(ax, m);
    float py = __shfl_xor(ay, m);
    float f = (k & m) ? sn : -sn;
    ax = c * ax + f * px;
    ay = c * ay + f * py;
}

__device__ inline void cnot_step(float& ax, float& ay, int k, int mc, int mt) {
    float px = __shfl_xor(ax, mt);
    float py = __shfl_xor(ay, mt);
    if (k & mc) { ax = px; ay = py; }
}

__global__ __launch_bounds__(1024) void build_A_kernel(
        const float* __restrict__ conv, const float* __restrict__ pool,
        const float* __restrict__ fcw, float* __restrict__ A) {
    const int tid  = threadIdx.x;
    const int col  = tid >> 5;
    const int k    = tid & 31;

    float ax = (k == col) ? 1.0f : 0.0f;
    float ay = 0.0f;

    int wires[NQ] = {0, 1, 2, 3, 4};
    int nw = NQ;
    const float S2 = 0.70710678118654752440f;

    #pragma unroll
    for (int l = 0; l < 2; ++l) {
        const float* w = conv + l * 15;
        for (int i = 0; i < nw; ++i) {
            const int a = wires[i], b = wires[(i + 1) % nw];
            const int ma = 16 >> a, mb = 16 >> b;
            // CNOT;RZ(b);CNOT == RZZ (diagonal)
            {
                float c, sn; __sincosf(0.5f * w[i], &sn, &c);
                float eim = ((((k & ma) != 0) ^ (((k & mb) != 0)))) ? sn : -sn;
                float nx = c * ax - eim * ay;
                float ny = c * ay + eim * ax;
                ax = nx; ay = ny;
            }
            rx_step(ax, ay, ma, S2, S2);
            rx_step(ax, ay, mb, S2, S2);
            cnot_step(ax, ay, k, ma, mb);
            rx_step(ax, ay, ma, S2, -S2);
            rx_step(ax, ay, mb, S2, -S2);
            // CZ;RZ(b);CZ == RZ(b)
            {
                float c, sn; __sincosf(0.5f * w[i + 2], &sn, &c);
                float eim = (k & mb) ? sn : -sn;
                float nx = c * ax - eim * ay;
                float ny = c * ay + eim * ax;
                ax = nx; ay = ny;
            }
        }
        // pool block
        {
            const float* pw = pool + l * 2;
            const int a = wires[0], b = wires[1];
            const int ma = 16 >> a, mb = 16 >> b;
            float c0, s0v, c1, s1v;
            __sincosf(0.5f * pw[0], &s0v, &c0);
            __sincosf(0.5f * pw[1], &s1v, &c1);
            ry_step(ax, ay, k, ma, c0, s0v);
            ry_step(ax, ay, k, mb, c1, s1v);
            cnot_step(ax, ay, k, ma, mb);
            // CRY(ctrl=b, tgt=a)
            {
                float px = __shfl_xor(ax, ma);
                float py = __shfl_xor(ay, ma);
                if (k & mb) {
                    float f = (k & ma) ? s0v : -s0v;
                    float nx = c0 * ax + f * px;
                    float ny = c0 * ay + f * py;
                    ax = nx; ay = ny;
                }
            }
            // CRX(ctrl=a, tgt=b)
            {
                float px = __shfl_xor(ax, mb);
                float py = __shfl_xor(ay, mb);
                if (k & ma) {
                    float nx = c1 * ax + s1v * py;
                    float ny = c1 * ay - s1v * px;
                    ax = nx; ay = ny;
                }
            }
            cnot_step(ax, ay, k, mb, ma);
        }
        for (int q = 0; q < nw - 1; ++q) wires[q] = wires[q + 1];
        nw--;
    }

    __shared__ float2 U[DIM][DIM + 1];
    U[col][k] = make_float2(ax, ay);
    __syncthreads();

    // measured wires [2,3] -> masks 4 and 2
    const int s = tid >> 5, t = tid & 31;
    const float w00 = fcw[0], w01 = fcw[1], w10 = fcw[2], w11 = fcw[3];
    float acc0 = 0.0f, acc1 = 0.0f;
    #pragma unroll
    for (int kk = 0; kk < DIM; ++kk) {
        float2 us = U[s][kk];
        float2 ut = U[t][kk];
        float d = us.x * ut.x + us.y * ut.y;
        float d2 = (kk & 4) ? -d : d;
        float d3 = (kk & 2) ? -d : d;
        acc0 += w00 * d2 + w01 * d3;
        acc1 += w10 * d2 + w11 * d3;
    }
    float f0 = (t < s) ? 0.0f : ((t == s) ? acc0 : 2.0f * acc0);
    float f1 = (t < s) ? 0.0f : ((t == s) ? acc1 : 2.0f * acc1);
    A[s * DIM + t]             = f0;
    A[DIM * DIM + s * DIM + t] = f1;
}

// ---------------- Kernel 2: per-batch-element evaluation ----------------
// A is read with wave-uniform compile-time indices -> scalar s_load path
// (SGPR operand into v_fmac), no LDS on the hot path.
__global__ __launch_bounds__(256) void qcnn_eval_kernel(
        const float* __restrict__ x, const float* __restrict__ A,
        const float* __restrict__ fcb, float* __restrict__ out, int nB) {
    // stage x coalesced through LDS (stride 5 is coprime to 32 banks -> conflict-free)
    __shared__ float xs[256 * NQ];
    const int base = blockIdx.x * 256 * NQ;
    #pragma unroll
    for (int i = 0; i < NQ; ++i) {
        int idx = threadIdx.x + i * 256;
        xs[idx] = x[base + idx];
    }
    __syncthreads();

    const int b = blockIdx.x * 256 + threadIdx.x;
    if (b >= nB) return;

    float cs[NQ], sn[NQ];
    #pragma unroll
    for (int q = 0; q < NQ; ++q) {
        float xv = xs[threadIdx.x * NQ + q];
        __sincosf(0.5f * xv, &sn[q], &cs[q]);
    }
    float v01[4];
    v01[0] = cs[0] * cs[1]; v01[1] = cs[0] * sn[1];
    v01[2] = sn[0] * cs[1]; v01[3] = sn[0] * sn[1];
    float v23[4];
    v23[0] = cs[2] * cs[3]; v23[1] = cs[2] * sn[3];
    v23[2] = sn[2] * cs[3]; v23[3] = sn[2] * sn[3];
    float v234[8];
    #pragma unroll
    for (int i = 0; i < 4; ++i) {
        v234[2 * i]     = v23[i] * cs[4];
        v234[2 * i + 1] = v23[i] * sn[4];
    }
    float s0[DIM];
    #pragma unroll
    for (int s = 0; s < DIM; ++s) s0[s] = v01[s >> 3] * v234[s & 7];

    // out[c] = s0^T Afold_c s0 + fcb[c]; A indices are compile-time constants
    // -> uniform scalar loads, v_fmac_f32 with SGPR matrix operand.
    float res0 = fcb[0], res1 = fcb[1];
    #pragma unroll
    for (int si = 0; si < DIM; ++si) {
        float row0 = 0.0f, row1 = 0.0f;
        #pragma unroll
        for (int t = si; t < DIM; ++t) {
            row0 = fmaf(A[si * DIM + t],             s0[t], row0);
            row1 = fmaf(A[DIM * DIM + si * DIM + t], s0[t], row1);
        }
        res0 = fmaf(s0[si], row0, res0);
        res1 = fmaf(s0[si], row1, res1);
    }
    reinterpret_cast<float2*>(out)[b] = make_float2(res0, res1);
}

// ---------------- launch ----------------
extern "C" void kernel_launch(void* const* d_in, const int* in_sizes, int n_in,
                              void* d_out, int out_size, void* d_ws, size_t ws_size,
                              hipStream_t stream) {
    const float* x    = (const float*)d_in[0];
    const float* conv = (const float*)d_in[1];
    const float* pool = (const float*)d_in[2];
    const float* fcw  = (const float*)d_in[3];
    const float* fcb  = (const float*)d_in[4];
    float* out = (float*)d_out;
    float* A   = (float*)d_ws;   // 2*32*32 floats = 8 KB

    const int nB = in_sizes[0] / NQ;

    hipLaunchKernelGGL(build_A_kernel, dim3(1), dim3(1024), 0, stream,
                       conv, pool, fcw, A);
    hipLaunchKernelGGL(qcnn_eval_kernel, dim3((nB + 255) / 256), dim3(256), 0, stream,
                       x, A, fcb, out, nB);
}

// Round 3
// 83.159 us; speedup vs baseline: 1.0838x; 1.0076x over previous
//
#include <hip/hip_runtime.h>
#include <math.h>

#define NQ 5
#define DIM 32

// ---------------- Kernel 1: build Pauli-basis coefficients coef[2][243] ----------------
// Phase A: 32 half-waves each simulate one basis column of U in registers (shfl_xor).
// Phase B: A_c[s][t] = sum_k w_c(k) * Re(conj(U[k,s]) U[k,t])  (real symmetric, 2 classes)
// Phase C: coef_c[P] = (1/32) * sum_s (-1)^popc(s&zmask) * A_c[s][s^xmask],  P in {I,Z,X}^5
//          out_c = sum_P coef_c[P] * prod_q t_q(P_q),  t(I)=1, t(Z)=cos x_q, t(X)=sin x_q
// Bit convention: qubit q <-> bit (4-q), mask m = 16>>q (q0 = MSB).

__device__ inline void rx_step(float& ax, float& ay, int m, float c, float sn) {
    float px = __shfl_xor(ax, m);
    float py = __shfl_xor(ay, m);
    float nx = c * ax + sn * py;
    float ny = c * ay - sn * px;
    ax = nx; ay = ny;
}

__device__ inline void ry_step(float& ax, float& ay, int k, int m, float c, float sn) {
    float px = __shfl_xor(ax, m);
    float py = __shfl_xor(ay, m);
    float f = (k & m) ? sn : -sn;
    ax = c * ax + f * px;
    ay = c * ay + f * py;
}

__device__ inline void cnot_step(float& ax, float& ay, int k, int mc, int mt) {
    float px = __shfl_xor(ax, mt);
    float py = __shfl_xor(ay, mt);
    if (k & mc) { ax = px; ay = py; }
}

__global__ __launch_bounds__(1024) void build_coef_kernel(
        const float* __restrict__ conv, const float* __restrict__ pool,
        const float* __restrict__ fcw, const float* __restrict__ fcb,
        float* __restrict__ coef) {
    const int tid  = threadIdx.x;
    const int col  = tid >> 5;
    const int k    = tid & 31;

    float ax = (k == col) ? 1.0f : 0.0f;
    float ay = 0.0f;

    int wires[NQ] = {0, 1, 2, 3, 4};
    int nw = NQ;
    const float S2 = 0.70710678118654752440f;

    #pragma unroll
    for (int l = 0; l < 2; ++l) {
        const float* w = conv + l * 15;
        for (int i = 0; i < nw; ++i) {
            const int a = wires[i], b = wires[(i + 1) % nw];
            const int ma = 16 >> a, mb = 16 >> b;
            // CNOT;RZ(b);CNOT == RZZ (diagonal, parity phase)
            {
                float c, sn; __sincosf(0.5f * w[i], &sn, &c);
                float eim = ((((k & ma) != 0) ^ (((k & mb) != 0)))) ? sn : -sn;
                float nx = c * ax - eim * ay;
                float ny = c * ay + eim * ax;
                ax = nx; ay = ny;
            }
            rx_step(ax, ay, ma, S2, S2);
            rx_step(ax, ay, mb, S2, S2);
            cnot_step(ax, ay, k, ma, mb);
            rx_step(ax, ay, ma, S2, -S2);
            rx_step(ax, ay, mb, S2, -S2);
            // CZ;RZ(b);CZ == RZ(b)
            {
                float c, sn; __sincosf(0.5f * w[i + 2], &sn, &c);
                float eim = (k & mb) ? sn : -sn;
                float nx = c * ax - eim * ay;
                float ny = c * ay + eim * ax;
                ax = nx; ay = ny;
            }
        }
        // pool block
        {
            const float* pw = pool + l * 2;
            const int a = wires[0], b = wires[1];
            const int ma = 16 >> a, mb = 16 >> b;
            float c0, s0v, c1, s1v;
            __sincosf(0.5f * pw[0], &s0v, &c0);
            __sincosf(0.5f * pw[1], &s1v, &c1);
            ry_step(ax, ay, k, ma, c0, s0v);
            ry_step(ax, ay, k, mb, c1, s1v);
            cnot_step(ax, ay, k, ma, mb);
            // CRY(ctrl=b, tgt=a)
            {
                float px = __shfl_xor(ax, ma);
                float py = __shfl_xor(ay, ma);
                if (k & mb) {
                    float f = (k & ma) ? s0v : -s0v;
                    float nx = c0 * ax + f * px;
                    float ny = c0 * ay + f * py;
                    ax = nx; ay = ny;
                }
            }
            // CRX(ctrl=a, tgt=b)
            {
                float px = __shfl_xor(ax, mb);
                float py = __shfl_xor(ay, mb);
                if (k & ma) {
                    float nx = c1 * ax + s1v * py;
                    float ny = c1 * ay - s1v * px;
                    ax = nx; ay = ny;
                }
            }
            cnot_step(ax, ay, k, mb, ma);
        }
        for (int q = 0; q < nw - 1; ++q) wires[q] = wires[q + 1];
        nw--;
    }

    __shared__ float2 U[DIM][DIM + 1];
    U[col][k] = make_float2(ax, ay);
    __syncthreads();

    // Phase B: full symmetric A (no triangular fold). measured wires [2,3] -> masks 4, 2
    const int s = tid >> 5, t = tid & 31;
    const float w00 = fcw[0], w01 = fcw[1], w10 = fcw[2], w11 = fcw[3];
    float acc0 = 0.0f, acc1 = 0.0f;
    #pragma unroll
    for (int kk = 0; kk < DIM; ++kk) {
        float2 us = U[s][kk];
        float2 ut = U[t][kk];
        float d = us.x * ut.x + us.y * ut.y;
        float d2 = (kk & 4) ? -d : d;
        float d3 = (kk & 2) ? -d : d;
        acc0 += w00 * d2 + w01 * d3;
        acc1 += w10 * d2 + w11 * d3;
    }
    __shared__ float A0[DIM][DIM + 1], A1[DIM][DIM + 1];
    A0[s][t] = acc0;
    A1[s][t] = acc1;
    __syncthreads();

    // Phase C: Pauli transform. 486 threads, one (class, P) each.
    if (tid < 486) {
        const int cls = tid / 243;
        int r = tid % 243;
        const int pp = r;
        int dgt[NQ];
        dgt[4] = r % 3; r /= 3;
        dgt[3] = r % 3; r /= 3;
        dgt[2] = r % 3; r /= 3;
        dgt[1] = r % 3; r /= 3;
        dgt[0] = r;
        int xmask = 0, zmask = 0;
        #pragma unroll
        for (int q = 0; q < NQ; ++q) {
            const int m = 16 >> q;
            if (dgt[q] == 1) zmask |= m;
            else if (dgt[q] == 2) xmask |= m;
        }
        const float (*Ac)[DIM + 1] = cls ? A1 : A0;
        float val = 0.0f;
        #pragma unroll
        for (int ss = 0; ss < DIM; ++ss) {
            float a = Ac[ss][ss ^ xmask];
            val += (__popc(ss & zmask) & 1) ? -a : a;
        }
        val *= (1.0f / 32.0f);
        if (pp == 0) val += fcb[cls];   // fold bias into the all-identity term
        coef[cls * 243 + pp] = val;
    }
}

// ---------------- Kernel 2: per-batch-element evaluation (nested Horner over {I,Z,X}^5) ----------------
// coef reads are wave-uniform compile-time-indexed -> scalar s_load path.
// 484 FMA + 5 sincos per element.
__global__ __launch_bounds__(256) void qcnn_eval_kernel(
        const float* __restrict__ x, const float* __restrict__ C,
        float* __restrict__ out, int nB) {
    __shared__ float xs[256 * NQ];
    const int base = blockIdx.x * 256 * NQ;
    #pragma unroll
    for (int i = 0; i < NQ; ++i) {
        int idx = threadIdx.x + i * 256;
        xs[idx] = x[base + idx];
    }
    __syncthreads();

    const int b = blockIdx.x * 256 + threadIdx.x;
    if (b >= nB) return;

    float u[NQ], v[NQ];   // u = cos(x), v = sin(x)  (FULL angle)
    #pragma unroll
    for (int q = 0; q < NQ; ++q) {
        float xv = xs[threadIdx.x * NQ + q];
        __sincosf(xv, &v[q], &u[q]);
    }

    float res[2];
    #pragma unroll
    for (int cls = 0; cls < 2; ++cls) {
        const float* Cc = C + cls * 243;
        float lvl3[27];
        #pragma unroll
        for (int i = 0; i < 27; ++i) {
            float e0 = fmaf(v[4], Cc[9 * i + 2], fmaf(u[4], Cc[9 * i + 1], Cc[9 * i + 0]));
            float e1 = fmaf(v[4], Cc[9 * i + 5], fmaf(u[4], Cc[9 * i + 4], Cc[9 * i + 3]));
            float e2 = fmaf(v[4], Cc[9 * i + 8], fmaf(u[4], Cc[9 * i + 7], Cc[9 * i + 6]));
            lvl3[i] = fmaf(v[3], e2, fmaf(u[3], e1, e0));
        }
        float lvl2[9];
        #pragma unroll
        for (int i = 0; i < 9; ++i)
            lvl2[i] = fmaf(v[2], lvl3[3 * i + 2], fmaf(u[2], lvl3[3 * i + 1], lvl3[3 * i]));
        float lvl1[3];
        #pragma unroll
        for (int i = 0; i < 3; ++i)
            lvl1[i] = fmaf(v[1], lvl2[3 * i + 2], fmaf(u[1], lvl2[3 * i + 1], lvl2[3 * i]));
        res[cls] = fmaf(v[0], lvl1[2], fmaf(u[0], lvl1[1], lvl1[0]));
    }
    reinterpret_cast<float2*>(out)[b] = make_float2(res[0], res[1]);
}

// ---------------- launch ----------------
extern "C" void kernel_launch(void* const* d_in, const int* in_sizes, int n_in,
                              void* d_out, int out_size, void* d_ws, size_t ws_size,
                              hipStream_t stream) {
    const float* x    = (const float*)d_in[0];
    const float* conv = (const float*)d_in[1];
    const float* pool = (const float*)d_in[2];
    const float* fcw  = (const float*)d_in[3];
    const float* fcb  = (const float*)d_in[4];
    float* out  = (float*)d_out;
    float* coef = (float*)d_ws;   // 2*243 floats = 1944 B

    const int nB = in_sizes[0] / NQ;

    hipLaunchKernelGGL(build_coef_kernel, dim3(1), dim3(1024), 0, stream,
                       conv, pool, fcw, fcb, coef);
    hipLaunchKernelGGL(qcnn_eval_kernel, dim3((nB + 255) / 256), dim3(256), 0, stream,
                       x, coef, out, nB);
}